// Round 10
// baseline (258.886 us; speedup 1.0000x reference)
//
#include <hip/hip_runtime.h>
#include <stdint.h>

#define DCAP   128
#define CHUNK  1024
#define LOG_TAB 19
#define TAB_SIZE (1u << LOG_TAB)
#define TAB_MASK (TAB_SIZE - 1u)
#define KEMPTY 0xFFFFFFFFu
#define NSHARD 64

typedef unsigned int uintv4 __attribute__((ext_vector_type(4)));

// ---------------- sharded grid barrier (no threadfence; atomics only) -------
// bar: NSHARD counters spread 128B apart (cumulative arrivals, zeroed pre-launch)
// gen: NSHARD generation flags spread 128B apart (zeroed pre-launch)
__device__ __forceinline__ void gbar(int* bar, int* gen, int NB, int phase) {
    __syncthreads();
    if (threadIdx.x == 0)
        atomicAdd(&bar[(blockIdx.x & (NSHARD - 1)) << 5], 1);
    if (blockIdx.x == 0) {
        if (threadIdx.x < 64) {                 // leader wave: parallel sweep
            int target = NB * phase;            // arrivals are cumulative
            for (;;) {
                int s = atomicAdd(&bar[threadIdx.x << 5], 0);
                #pragma unroll
                for (int off = 32; off > 0; off >>= 1) s += __shfl_down(s, off);
                s = __shfl(s, 0);
                if (s >= target) break;
                __builtin_amdgcn_s_sleep(8);
            }
            atomicExch(&gen[threadIdx.x << 5], phase);   // 64-way parallel release
        }
    } else if (threadIdx.x == 0) {
        int* mg = &gen[(blockIdx.x & (NSHARD - 1)) << 5];
        while (atomicAdd(mg, 0) < phase) __builtin_amdgcn_s_sleep(64);
    }
    __syncthreads();
}

// ---------------- pack slice: permuted ballot layout (verified R5..R9) ------
// word g*8 + 2k+half, bit b  <->  float g*256 + 128*half + 4b + k
__device__ __forceinline__ void packSlice(const float* __restrict__ W,
                                          uint32_t* __restrict__ Wbits,
                                          long long lo, long long hi,
                                          int NB, int firstBlock) {
    if ((int)blockIdx.x < firstBlock) return;
    long long wv  = (((long long)((int)blockIdx.x - firstBlock)) * 256 + threadIdx.x) >> 6;
    long long nwv = (((long long)(NB - firstBlock)) * 256) >> 6;
    int lane = threadIdx.x & 63;
    int k = lane >> 1, half = lane & 1;
    const uintv4* W4 = (const uintv4*)W;
    for (long long g = lo + wv; g < hi; g += nwv) {
        uintv4 u = W4[g * 64 + lane];
        unsigned long long m0 = __ballot((int)u.x < 0);
        unsigned long long m1 = __ballot((int)u.y < 0);
        unsigned long long m2 = __ballot((int)u.z < 0);
        unsigned long long m3 = __ballot((int)u.w < 0);
        if (lane < 8) {
            unsigned long long m = (k == 0) ? m0 : (k == 1) ? m1 : (k == 2) ? m2 : m3;
            Wbits[g * 8 + lane] = half ? (uint32_t)(m >> 32) : (uint32_t)m;
        }
    }
}

// ---------------- cooperative megakernel: init+degree+insert+hist+prefix+pos+pack
__global__ __launch_bounds__(256, 8) void k_mega(
    const float* __restrict__ W, const int* __restrict__ ei,
    int* degree, int* hist, int* chunkHist, int* pos,
    unsigned int* tab, int* uA, int* uB, int* count,
    int* neg, uint32_t* Wbits, int* bar, int* gen,
    int N, int E, int D, int numChunks, int nLargeBlocks, long long G, int NB)
{
    __shared__ int smem[CHUNK];
    const int tid = threadIdx.x;
    const long long TT = (long long)NB * 256;
    const long long gt = (long long)blockIdx.x * 256 + tid;

    // P0: init. Regions read ATOMICALLY within this kernel get atomic stores;
    // neg is only read by the next kernel (boundary flush) -> normal stores.
    for (long long j = gt; j < N; j += TT) atomicExch(&degree[j], 0);
    for (long long j = gt; j < E + 1; j += TT) atomicExch(&hist[j], 0);
    if (gt == 0) atomicExch(count, 0);
    for (long long j = gt; j < D; j += TT) neg[j] = 0;
    for (long long j = gt; j < (long long)TAB_SIZE; j += TT) atomicExch(&tab[j], KEMPTY);
    packSlice(W, Wbits, 0, G / 5, NB, 0);
    gbar(bar, gen, NB, 1);

    // P1: in-degree + dedup insert (stores NODE ids; pos resolved in accum)
    for (long long e = gt; e < E; e += TT) {
        int a = ei[e], b = ei[E + e];
        atomicAdd(&degree[b], 1);
        int r = min(a, b), c = max(a, b);
        unsigned int key = ((unsigned int)r << 16) | (unsigned int)c;
        unsigned int h = (key * 2654435761u) >> (32 - LOG_TAB);
        for (;;) {
            unsigned int old = atomicCAS(&tab[h], KEMPTY, key);
            if (old == KEMPTY) { int idx = atomicAdd(count, 1); uA[idx] = r; uB[idx] = c; break; }
            if (old == key) break;
            h = (h + 1) & TAB_MASK;
        }
    }
    packSlice(W, Wbits, G / 5, 2 * G / 5, NB, 0);
    gbar(bar, gen, NB, 2);

    // P2: per-chunk degree histogram (LDS), atomic degree reads
    if ((int)blockIdx.x < numChunks) {
        if (tid < DCAP) smem[tid] = 0;
        __syncthreads();
        for (int q = 0; q < CHUNK / 256; ++q) {
            int j = blockIdx.x * CHUNK + q * 256 + tid;
            if (j < N) {
                int d = atomicAdd(&degree[j], 0);
                if (d < DCAP) atomicAdd(&smem[d], 1);
                else          atomicAdd(&hist[d], 1);
            }
        }
        __syncthreads();
        if (tid < DCAP) atomicExch(&chunkHist[blockIdx.x * DCAP + tid], smem[tid]);
    }
    packSlice(W, Wbits, 2 * G / 5, 3 * G / 5, NB, 0);
    gbar(bar, gen, NB, 3);

    // P3: prefix over chunks (block 0 only; 8-batched atomics for MLP)
    if (blockIdx.x == 0) {
        int tot = 0;
        if (tid < DCAP) {
            for (int c0 = 0; c0 < numChunks; c0 += 8) {
                int v[8];
                #pragma unroll
                for (int i = 0; i < 8; ++i)
                    v[i] = (c0 + i < numChunks) ? atomicAdd(&chunkHist[(c0 + i) * DCAP + tid], 0) : 0;
                #pragma unroll
                for (int i = 0; i < 8; ++i) tot += v[i];
            }
            smem[tid] = tot;
            atomicExch(&hist[tid], tot);
        }
        __syncthreads();
        if (tid < DCAP) {
            int run = 0;
            for (int d2 = 0; d2 < tid; ++d2) run += smem[d2];
            for (int c0 = 0; c0 < numChunks; c0 += 8) {
                int v[8];
                #pragma unroll
                for (int i = 0; i < 8; ++i)
                    v[i] = (c0 + i < numChunks) ? atomicAdd(&chunkHist[(c0 + i) * DCAP + tid], 0) : 0;
                #pragma unroll
                for (int i = 0; i < 8; ++i)
                    if (c0 + i < numChunks) { atomicExch(&chunkHist[(c0 + i) * DCAP + tid], run); run += v[i]; }
            }
        }
    }
    packSlice(W, Wbits, 3 * G / 5, 4 * G / 5, NB, 1);
    gbar(bar, gen, NB, 4);

    // P4: stable rank -> pos (normal stores; read post-boundary)
    if ((int)blockIdx.x < numChunks) {
        for (int q = 0; q < CHUNK / 256; ++q) {
            int j = blockIdx.x * CHUNK + q * 256 + tid;
            smem[q * 256 + tid] = (j < N) ? atomicAdd(&degree[j], 0) : -1;
        }
        __syncthreads();
        int base0 = blockIdx.x * CHUNK;
        for (int q = 0; q < CHUNK / 256; ++q) {
            int idx = tid * (CHUNK / 256) + q;
            int j = base0 + idx;
            int d = smem[idx];
            if (j < N && d >= 0 && d < DCAP) {
                int r = 0;
                for (int t2 = 0; t2 < idx; ++t2) r += (smem[t2] == d);
                pos[j] = atomicAdd(&chunkHist[blockIdx.x * DCAP + d], 0) + r;
            }
        }
    } else if ((int)blockIdx.x < numChunks + nLargeBlocks) {
        // deg >= DCAP fallback (never triggered for Poisson(2); correctness net)
        int d = DCAP + ((int)blockIdx.x - numChunks) * 256 + tid;
        if (d <= E && atomicAdd(&hist[d], 0) != 0) {
            int base = 0;
            for (int d2 = 0; d2 < d; ++d2) base += atomicAdd(&hist[d2], 0);
            int cnt2 = 0;
            for (int j = 0; j < N; ++j)
                if (atomicAdd(&degree[j], 0) == d) { pos[j] = base + cnt2; ++cnt2; }
        }
    }
    packSlice(W, Wbits, 4 * G / 5, G, NB, numChunks + nLargeBlocks);
    // no final barrier: Wbits/pos/uA/uB cross to k_accum_bits via kernel boundary
}

// ---------------- accum: neg[w*32+d] += xor-popcount over unique edges ------
__global__ __launch_bounds__(256) void k_accum_bits(const uint32_t* __restrict__ Wbits,
                                                    const int* __restrict__ pos,
                                                    const int* __restrict__ uA,
                                                    const int* __restrict__ uB,
                                                    const int* __restrict__ count,
                                                    int* __restrict__ neg, int D) {
    __shared__ int sneg[1024];
    int t = threadIdx.x, w = t & 31, slot = t >> 5;
    int wpr = D / 32;                       // requires wpr <= 32 (D <= 1024)
    for (int i = t; i < D; i += 256) sneg[i] = 0;
    __syncthreads();
    int cnt = *count;
    int cnts[32];
    #pragma unroll
    for (int d = 0; d < 32; ++d) cnts[d] = 0;
    if (w < wpr) {
        for (int base = blockIdx.x * 8; base < cnt; base += gridDim.x * 8) {
            int e = base + slot;
            if (e < cnt) {
                size_t ra = (size_t)pos[uA[e]] * wpr;
                size_t rb = (size_t)pos[uB[e]] * wpr;
                uint32_t x = Wbits[ra + w] ^ Wbits[rb + w];
                #pragma unroll
                for (int d = 0; d < 32; ++d) cnts[d] += (x >> d) & 1u;
            }
        }
        #pragma unroll
        for (int d = 0; d < 32; ++d) atomicAdd(&sneg[w * 32 + d], cnts[d]);
    }
    __syncthreads();
    for (int i = t; i < D; i += 256)
        if (sneg[i]) atomicAdd(&neg[i], sneg[i]);
}

// ---------------- finalize: out[d] = cnt - 2*neg[map(d)] --------------------
__global__ void k_finalize(const int* __restrict__ neg, const int* __restrict__ count,
                           float* __restrict__ out, int D, int permuted) {
    int d = blockIdx.x * blockDim.x + threadIdx.x;
    if (d >= D) return;
    int ni;
    if (permuted) {
        int off = d & 255, q = d >> 8;
        int k = off & 3, l = off >> 2, half = l >> 5, b = l & 31;
        ni = (q * 8 + 2 * k + half) * 32 + b;
    } else {
        ni = d;
    }
    out[d] = (float)(*count - 2 * neg[ni]);
}

// ================= fallback chain (old R7 path, node-id insert) =============
__global__ void k_degree(const int* __restrict__ col, int* __restrict__ degree, int E) {
    int e = blockIdx.x * blockDim.x + threadIdx.x;
    if (e < E) atomicAdd(&degree[col[e]], 1);
}
__global__ void k_chunk_hist(const int* __restrict__ degree, int* __restrict__ hist,
                             int* __restrict__ chunkHist, int N) {
    __shared__ int sh[DCAP];
    int t = threadIdx.x;
    if (t < DCAP) sh[t] = 0;
    __syncthreads();
    int j = blockIdx.x * CHUNK + t;
    if (j < N) {
        int d = degree[j];
        if (d < DCAP) atomicAdd(&sh[d], 1);
        else          atomicAdd(&hist[d], 1);
    }
    __syncthreads();
    if (t < DCAP) chunkHist[blockIdx.x * DCAP + t] = sh[t];
}
__global__ void k_chunk_prefix(int* __restrict__ hist, int* __restrict__ chunkHist,
                               int numChunks) {
    __shared__ int stot[DCAP];
    int d = threadIdx.x;
    int tot = 0;
    for (int c = 0; c < numChunks; ++c) tot += chunkHist[c * DCAP + d];
    stot[d] = tot;
    hist[d] = tot;
    __syncthreads();
    int run = 0;
    for (int d2 = 0; d2 < d; ++d2) run += stot[d2];
    for (int c = 0; c < numChunks; ++c) {
        int tmp = chunkHist[c * DCAP + d];
        chunkHist[c * DCAP + d] = run;
        run += tmp;
    }
}
__global__ __launch_bounds__(CHUNK) void k_pos(const int* __restrict__ degree,
                                               const int* __restrict__ chunkBase,
                                               const int* __restrict__ hist,
                                               int* __restrict__ pos,
                                               int N, int E, int numChunks) {
    int t = threadIdx.x;
    if ((int)blockIdx.x < numChunks) {
        __shared__ int sdeg[CHUNK];
        int j = blockIdx.x * CHUNK + t;
        int d = (j < N) ? degree[j] : -1;
        sdeg[t] = d;
        __syncthreads();
        if (j < N && d < DCAP && d >= 0) {
            int r = 0;
            for (int t2 = 0; t2 < t; ++t2) r += (sdeg[t2] == d);
            pos[j] = chunkBase[blockIdx.x * DCAP + d] + r;
        }
    } else {
        int d = DCAP + (blockIdx.x - numChunks) * CHUNK + t;
        if (d > E) return;
        if (hist[d] == 0) return;
        int base = 0;
        for (int d2 = 0; d2 < d; ++d2) base += hist[d2];
        int cnt = 0;
        for (int j = 0; j < N; ++j)
            if (degree[j] == d) pos[j] = base + cnt++;
    }
}
__global__ __launch_bounds__(256) void k_pack_ballot(const float* __restrict__ W,
                                                     uint32_t* __restrict__ Wbits,
                                                     long long G) {
    long long wv = ((long long)blockIdx.x * 256 + threadIdx.x) >> 6;
    long long nwv = ((long long)gridDim.x * 256) >> 6;
    int lane = threadIdx.x & 63;
    int k = lane >> 1, half = lane & 1;
    const uintv4* W4 = (const uintv4*)W;
    for (long long g = wv; g < G; g += nwv) {
        uintv4 u = W4[g * 64 + lane];
        unsigned long long m0 = __ballot((int)u.x < 0);
        unsigned long long m1 = __ballot((int)u.y < 0);
        unsigned long long m2 = __ballot((int)u.z < 0);
        unsigned long long m3 = __ballot((int)u.w < 0);
        if (lane < 8) {
            unsigned long long m = (k == 0) ? m0 : (k == 1) ? m1 : (k == 2) ? m2 : m3;
            Wbits[g * 8 + lane] = half ? (uint32_t)(m >> 32) : (uint32_t)m;
        }
    }
}
__global__ __launch_bounds__(256) void k_pack_linear(const float* __restrict__ W,
                                                     uint32_t* __restrict__ Wbits, long long NW) {
    long long widx = (long long)blockIdx.x * 256 + threadIdx.x;
    if (widx >= NW) return;
    const uintv4* src = (const uintv4*)(W + widx * 32);
    uint32_t word = 0;
    #pragma unroll
    for (int q = 0; q < 8; ++q) {
        uintv4 u = src[q];
        word |= (u.x >> 31) << (4 * q + 0);
        word |= (u.y >> 31) << (4 * q + 1);
        word |= (u.z >> 31) << (4 * q + 2);
        word |= (u.w >> 31) << (4 * q + 3);
    }
    Wbits[widx] = word;
}
__global__ void k_insert_nodes(const int* __restrict__ ei, unsigned int* __restrict__ tab,
                               int* __restrict__ uA, int* __restrict__ uB,
                               int* __restrict__ count, int E) {
    int e = blockIdx.x * blockDim.x + threadIdx.x;
    if (e >= E) return;
    int a = ei[e], b = ei[E + e];
    int r = min(a, b), c = max(a, b);
    unsigned int key = ((unsigned int)r << 16) | (unsigned int)c;
    unsigned int h = (key * 2654435761u) >> (32 - LOG_TAB);
    while (true) {
        unsigned int old = atomicCAS(&tab[h], KEMPTY, key);
        if (old == KEMPTY) { int idx = atomicAdd(count, 1); uA[idx] = r; uB[idx] = c; return; }
        if (old == key) return;
        h = (h + 1) & TAB_MASK;
    }
}

static inline size_t align256(size_t x) { return (x + 255) & ~(size_t)255; }

extern "C" void kernel_launch(void* const* d_in, const int* in_sizes, int n_in,
                              void* d_out, int out_size, void* d_ws, size_t ws_size,
                              hipStream_t stream) {
    const float* W  = (const float*)d_in[0];
    const int*   ei = (const int*)d_in[1];
    const int D = out_size;               // 1024
    const int N = in_sizes[0] / D;        // 50000
    const int E = in_sizes[1] / 2;        // 100000
    const int numChunks = (N + CHUNK - 1) / CHUNK;
    const int nLargeBlocks256 = (E + 1 - DCAP + 255) / 256;
    const long long ND = (long long)N * D;
    const long long NW = ND / 32;
    const long long G  = ND / 256;

    char* p = (char*)d_ws;
    int* bar          = (int*)p;          p += NSHARD * 32 * 4;   // 8 KB
    int* gen          = (int*)p;          p += NSHARD * 32 * 4;   // 8 KB
    char* zbase = p;                                               // fallback zero region
    int* degree       = (int*)p;          p += align256((size_t)N * 4);
    int* hist         = (int*)p;          p += align256((size_t)(E + 1) * 4);
    int* count        = (int*)p;          p += 256;
    int* neg          = (int*)p;          p += align256((size_t)D * 4);
    size_t zbytes = (size_t)(p - zbase);
    int* chunkHist    = (int*)p;          p += align256((size_t)numChunks * DCAP * 4);
    int* pos          = (int*)p;          p += align256((size_t)N * 4);
    unsigned int* tab = (unsigned int*)p; p += (size_t)TAB_SIZE * 4;
    int* uA           = (int*)p;          p += align256((size_t)E * 4);
    int* uB           = (int*)p;          p += align256((size_t)E * 4);
    uint32_t* Wbits   = (uint32_t*)p;     p += align256((size_t)NW * 4);

    int dev = 0;
    hipGetDevice(&dev);
    int cus = 0;
    hipDeviceGetAttribute(&cus, hipDeviceAttributeMultiprocessorCount, dev);
    int maxB = 0;
    hipOccupancyMaxActiveBlocksPerMultiprocessor(&maxB, k_mega, 256, 0);
    int NB = cus * maxB;
    if (NB > 2048) NB = 2048;

    bool useMega = (D % 256 == 0) && (D <= 1024) &&
                   (NB >= numChunks + nLargeBlocks256 + 64);

    if (useMega) {
        hipMemsetAsync(bar, 0, NSHARD * 32 * 4 * 2, stream);   // bar + gen
        const float* Wp = W; const int* eip = ei;
        int Np = N, Ep = E, Dp = D, nc = numChunks, nl = nLargeBlocks256, nb = NB;
        long long Gp = G;
        void* args[] = { (void*)&Wp, (void*)&eip, (void*)&degree, (void*)&hist,
                         (void*)&chunkHist, (void*)&pos, (void*)&tab, (void*)&uA,
                         (void*)&uB, (void*)&count, (void*)&neg, (void*)&Wbits,
                         (void*)&bar, (void*)&gen, (void*)&Np, (void*)&Ep,
                         (void*)&Dp, (void*)&nc, (void*)&nl, (void*)&Gp, (void*)&nb };
        hipError_t err = hipLaunchCooperativeKernel((void*)k_mega, dim3(NB), dim3(256),
                                                    args, 0, stream);
        if (err != hipSuccess) {
            (void)hipGetLastError();
            // occupancy-sized grid -> co-resident; plain launch as backup
            k_mega<<<NB, 256, 0, stream>>>(W, ei, degree, hist, chunkHist, pos, tab,
                                           uA, uB, count, neg, Wbits, bar, gen,
                                           N, E, D, numChunks, nLargeBlocks256, G, NB);
        }
        k_accum_bits<<<2048, 256, 0, stream>>>(Wbits, pos, uA, uB, count, neg, D);
        k_finalize<<<(D + 255) / 256, 256, 0, stream>>>(neg, count, (float*)d_out, D, 1);
    } else {
        hipMemsetAsync(zbase, 0, zbytes, stream);
        hipMemsetAsync(tab, 0xFF, (size_t)TAB_SIZE * 4, stream);
        k_degree<<<(E + 255) / 256, 256, 0, stream>>>(ei + E, degree, E);
        k_chunk_hist<<<numChunks, CHUNK, 0, stream>>>(degree, hist, chunkHist, N);
        k_chunk_prefix<<<1, DCAP, 0, stream>>>(hist, chunkHist, numChunks);
        int nLB = (E + 1 - DCAP + CHUNK - 1) / CHUNK;
        k_pos<<<numChunks + nLB, CHUNK, 0, stream>>>(degree, chunkHist, hist, pos,
                                                     N, E, numChunks);
        int permuted = (D % 256 == 0);
        if (permuted) k_pack_ballot<<<2048, 256, 0, stream>>>(W, Wbits, G);
        else          k_pack_linear<<<(int)((NW + 255) / 256), 256, 0, stream>>>(W, Wbits, NW);
        k_insert_nodes<<<(E + 255) / 256, 256, 0, stream>>>(ei, tab, uA, uB, count, E);
        k_accum_bits<<<2048, 256, 0, stream>>>(Wbits, pos, uA, uB, count, neg, D);
        k_finalize<<<(D + 255) / 256, 256, 0, stream>>>(neg, count, (float*)d_out, D, permuted);
    }
}

// Round 11
// 255.449 us; speedup vs baseline: 1.0135x; 1.0135x over previous
//
#include <hip/hip_runtime.h>
#include <stdint.h>

#define DCAP   128
#define CHUNK  1024
#define LOG_TAB 19
#define TAB_SIZE (1u << LOG_TAB)
#define TAB_MASK (TAB_SIZE - 1u)
#define KEMPTY 0xFFFFFFFFu
#define NSHARD 64

typedef unsigned int uintv4 __attribute__((ext_vector_type(4)));

// ---------------- sharded grid barrier (no threadfence; atomics only) -------
// bar: NSHARD counters spread 128B apart (cumulative arrivals, zeroed pre-launch)
// gen: NSHARD generation flags spread 128B apart (zeroed pre-launch)
__device__ __forceinline__ void gbar(int* bar, int* gen, int NB, int phase) {
    __syncthreads();
    if (threadIdx.x == 0)
        atomicAdd(&bar[(blockIdx.x & (NSHARD - 1)) << 5], 1);
    if (blockIdx.x == 0) {
        if (threadIdx.x < 64) {                 // leader wave: parallel sweep
            int target = NB * phase;            // arrivals are cumulative
            for (;;) {
                int s = atomicAdd(&bar[threadIdx.x << 5], 0);
                #pragma unroll
                for (int off = 32; off > 0; off >>= 1) s += __shfl_down(s, off);
                s = __shfl(s, 0);
                if (s >= target) break;
                __builtin_amdgcn_s_sleep(8);
            }
            atomicExch(&gen[threadIdx.x << 5], phase);   // 64-way parallel release
        }
    } else if (threadIdx.x == 0) {
        int* mg = &gen[(blockIdx.x & (NSHARD - 1)) << 5];
        while (atomicAdd(mg, 0) < phase) __builtin_amdgcn_s_sleep(64);
    }
    __syncthreads();
}

// ---------------- pack slice: permuted ballot layout (verified R5..R9) ------
// word g*8 + 2k+half, bit b  <->  float g*256 + 128*half + 4b + k
__device__ __forceinline__ void packSlice(const float* __restrict__ W,
                                          uint32_t* __restrict__ Wbits,
                                          long long lo, long long hi,
                                          int NB, int firstBlock) {
    if ((int)blockIdx.x < firstBlock) return;
    long long wv  = (((long long)((int)blockIdx.x - firstBlock)) * 256 + threadIdx.x) >> 6;
    long long nwv = (((long long)(NB - firstBlock)) * 256) >> 6;
    int lane = threadIdx.x & 63;
    int k = lane >> 1, half = lane & 1;
    const uintv4* W4 = (const uintv4*)W;
    for (long long g = lo + wv; g < hi; g += nwv) {
        uintv4 u = W4[g * 64 + lane];
        unsigned long long m0 = __ballot((int)u.x < 0);
        unsigned long long m1 = __ballot((int)u.y < 0);
        unsigned long long m2 = __ballot((int)u.z < 0);
        unsigned long long m3 = __ballot((int)u.w < 0);
        if (lane < 8) {
            unsigned long long m = (k == 0) ? m0 : (k == 1) ? m1 : (k == 2) ? m2 : m3;
            Wbits[g * 8 + lane] = half ? (uint32_t)(m >> 32) : (uint32_t)m;
        }
    }
}

// ---------------- cooperative megakernel: init+degree+insert+hist+prefix+pos+pack
__global__ __launch_bounds__(256, 8) void k_mega(
    const float* __restrict__ W, const int* __restrict__ ei,
    int* degree, int* hist, int* chunkHist, int* pos,
    unsigned int* tab, int* uA, int* uB, int* count,
    int* neg, uint32_t* Wbits, int* bar, int* gen,
    int N, int E, int D, int numChunks, int nLargeBlocks, long long G, int NB)
{
    __shared__ int smem[CHUNK];
    const int tid = threadIdx.x;
    const long long TT = (long long)NB * 256;
    const long long gt = (long long)blockIdx.x * 256 + tid;

    // P0: init. Regions read ATOMICALLY within this kernel get atomic stores;
    // neg is only read by the next kernel (boundary flush) -> normal stores.
    for (long long j = gt; j < N; j += TT) atomicExch(&degree[j], 0);
    for (long long j = gt; j < E + 1; j += TT) atomicExch(&hist[j], 0);
    if (gt == 0) atomicExch(count, 0);
    for (long long j = gt; j < D; j += TT) neg[j] = 0;
    for (long long j = gt; j < (long long)TAB_SIZE; j += TT) atomicExch(&tab[j], KEMPTY);
    packSlice(W, Wbits, 0, G / 5, NB, 0);
    gbar(bar, gen, NB, 1);

    // P1: in-degree + dedup insert (stores NODE ids; pos resolved in accum)
    for (long long e = gt; e < E; e += TT) {
        int a = ei[e], b = ei[E + e];
        atomicAdd(&degree[b], 1);
        int r = min(a, b), c = max(a, b);
        unsigned int key = ((unsigned int)r << 16) | (unsigned int)c;
        unsigned int h = (key * 2654435761u) >> (32 - LOG_TAB);
        for (;;) {
            unsigned int old = atomicCAS(&tab[h], KEMPTY, key);
            if (old == KEMPTY) { int idx = atomicAdd(count, 1); uA[idx] = r; uB[idx] = c; break; }
            if (old == key) break;
            h = (h + 1) & TAB_MASK;
        }
    }
    packSlice(W, Wbits, G / 5, 2 * G / 5, NB, 0);
    gbar(bar, gen, NB, 2);

    // P2: per-chunk degree histogram (LDS), atomic degree reads
    if ((int)blockIdx.x < numChunks) {
        if (tid < DCAP) smem[tid] = 0;
        __syncthreads();
        for (int q = 0; q < CHUNK / 256; ++q) {
            int j = blockIdx.x * CHUNK + q * 256 + tid;
            if (j < N) {
                int d = atomicAdd(&degree[j], 0);
                if (d < DCAP) atomicAdd(&smem[d], 1);
                else          atomicAdd(&hist[d], 1);
            }
        }
        __syncthreads();
        if (tid < DCAP) atomicExch(&chunkHist[blockIdx.x * DCAP + tid], smem[tid]);
    }
    packSlice(W, Wbits, 2 * G / 5, 3 * G / 5, NB, 0);
    gbar(bar, gen, NB, 3);

    // P3: prefix over chunks (block 0 only; 8-batched atomics for MLP)
    if (blockIdx.x == 0) {
        int tot = 0;
        if (tid < DCAP) {
            for (int c0 = 0; c0 < numChunks; c0 += 8) {
                int v[8];
                #pragma unroll
                for (int i = 0; i < 8; ++i)
                    v[i] = (c0 + i < numChunks) ? atomicAdd(&chunkHist[(c0 + i) * DCAP + tid], 0) : 0;
                #pragma unroll
                for (int i = 0; i < 8; ++i) tot += v[i];
            }
            smem[tid] = tot;
            atomicExch(&hist[tid], tot);
        }
        __syncthreads();
        if (tid < DCAP) {
            int run = 0;
            for (int d2 = 0; d2 < tid; ++d2) run += smem[d2];
            for (int c0 = 0; c0 < numChunks; c0 += 8) {
                int v[8];
                #pragma unroll
                for (int i = 0; i < 8; ++i)
                    v[i] = (c0 + i < numChunks) ? atomicAdd(&chunkHist[(c0 + i) * DCAP + tid], 0) : 0;
                #pragma unroll
                for (int i = 0; i < 8; ++i)
                    if (c0 + i < numChunks) { atomicExch(&chunkHist[(c0 + i) * DCAP + tid], run); run += v[i]; }
            }
        }
    }
    packSlice(W, Wbits, 3 * G / 5, 4 * G / 5, NB, 1);
    gbar(bar, gen, NB, 4);

    // P4: stable rank -> pos (normal stores; read post-boundary)
    if ((int)blockIdx.x < numChunks) {
        for (int q = 0; q < CHUNK / 256; ++q) {
            int j = blockIdx.x * CHUNK + q * 256 + tid;
            smem[q * 256 + tid] = (j < N) ? atomicAdd(&degree[j], 0) : -1;
        }
        __syncthreads();
        int base0 = blockIdx.x * CHUNK;
        for (int q = 0; q < CHUNK / 256; ++q) {
            int idx = tid * (CHUNK / 256) + q;
            int j = base0 + idx;
            int d = smem[idx];
            if (j < N && d >= 0 && d < DCAP) {
                int r = 0;
                for (int t2 = 0; t2 < idx; ++t2) r += (smem[t2] == d);
                pos[j] = atomicAdd(&chunkHist[blockIdx.x * DCAP + d], 0) + r;
            }
        }
    } else if ((int)blockIdx.x < numChunks + nLargeBlocks) {
        // deg >= DCAP fallback (never triggered for Poisson(2); correctness net)
        int d = DCAP + ((int)blockIdx.x - numChunks) * 256 + tid;
        if (d <= E && atomicAdd(&hist[d], 0) != 0) {
            int base = 0;
            for (int d2 = 0; d2 < d; ++d2) base += atomicAdd(&hist[d2], 0);
            int cnt2 = 0;
            for (int j = 0; j < N; ++j)
                if (atomicAdd(&degree[j], 0) == d) { pos[j] = base + cnt2; ++cnt2; }
        }
    }
    packSlice(W, Wbits, 4 * G / 5, G, NB, numChunks + nLargeBlocks);
    // no final barrier: Wbits/pos/uA/uB cross to k_accum_bits via kernel boundary
}

// ---------------- accum: neg[w*32+d] += xor-popcount over unique edges ------
__global__ __launch_bounds__(256) void k_accum_bits(const uint32_t* __restrict__ Wbits,
                                                    const int* __restrict__ pos,
                                                    const int* __restrict__ uA,
                                                    const int* __restrict__ uB,
                                                    const int* __restrict__ count,
                                                    int* __restrict__ neg, int D) {
    __shared__ int sneg[1024];
    int t = threadIdx.x, w = t & 31, slot = t >> 5;
    int wpr = D / 32;                       // requires wpr <= 32 (D <= 1024)
    for (int i = t; i < D; i += 256) sneg[i] = 0;
    __syncthreads();
    int cnt = *count;
    int cnts[32];
    #pragma unroll
    for (int d = 0; d < 32; ++d) cnts[d] = 0;
    if (w < wpr) {
        for (int base = blockIdx.x * 8; base < cnt; base += gridDim.x * 8) {
            int e = base + slot;
            if (e < cnt) {
                size_t ra = (size_t)pos[uA[e]] * wpr;
                size_t rb = (size_t)pos[uB[e]] * wpr;
                uint32_t x = Wbits[ra + w] ^ Wbits[rb + w];
                #pragma unroll
                for (int d = 0; d < 32; ++d) cnts[d] += (x >> d) & 1u;
            }
        }
        #pragma unroll
        for (int d = 0; d < 32; ++d) atomicAdd(&sneg[w * 32 + d], cnts[d]);
    }
    __syncthreads();
    for (int i = t; i < D; i += 256)
        if (sneg[i]) atomicAdd(&neg[i], sneg[i]);
}

// ---------------- finalize: out[d] = cnt - 2*neg[map(d)] --------------------
__global__ void k_finalize(const int* __restrict__ neg, const int* __restrict__ count,
                           float* __restrict__ out, int D, int permuted) {
    int d = blockIdx.x * blockDim.x + threadIdx.x;
    if (d >= D) return;
    int ni;
    if (permuted) {
        int off = d & 255, q = d >> 8;
        int k = off & 3, l = off >> 2, half = l >> 5, b = l & 31;
        ni = (q * 8 + 2 * k + half) * 32 + b;
    } else {
        ni = d;
    }
    out[d] = (float)(*count - 2 * neg[ni]);
}

// ================= fallback chain (old R7 path, node-id insert) =============
__global__ void k_degree(const int* __restrict__ col, int* __restrict__ degree, int E) {
    int e = blockIdx.x * blockDim.x + threadIdx.x;
    if (e < E) atomicAdd(&degree[col[e]], 1);
}
__global__ void k_chunk_hist(const int* __restrict__ degree, int* __restrict__ hist,
                             int* __restrict__ chunkHist, int N) {
    __shared__ int sh[DCAP];
    int t = threadIdx.x;
    if (t < DCAP) sh[t] = 0;
    __syncthreads();
    int j = blockIdx.x * CHUNK + t;
    if (j < N) {
        int d = degree[j];
        if (d < DCAP) atomicAdd(&sh[d], 1);
        else          atomicAdd(&hist[d], 1);
    }
    __syncthreads();
    if (t < DCAP) chunkHist[blockIdx.x * DCAP + t] = sh[t];
}
__global__ void k_chunk_prefix(int* __restrict__ hist, int* __restrict__ chunkHist,
                               int numChunks) {
    __shared__ int stot[DCAP];
    int d = threadIdx.x;
    int tot = 0;
    for (int c = 0; c < numChunks; ++c) tot += chunkHist[c * DCAP + d];
    stot[d] = tot;
    hist[d] = tot;
    __syncthreads();
    int run = 0;
    for (int d2 = 0; d2 < d; ++d2) run += stot[d2];
    for (int c = 0; c < numChunks; ++c) {
        int tmp = chunkHist[c * DCAP + d];
        chunkHist[c * DCAP + d] = run;
        run += tmp;
    }
}
__global__ __launch_bounds__(CHUNK) void k_pos(const int* __restrict__ degree,
                                               const int* __restrict__ chunkBase,
                                               const int* __restrict__ hist,
                                               int* __restrict__ pos,
                                               int N, int E, int numChunks) {
    int t = threadIdx.x;
    if ((int)blockIdx.x < numChunks) {
        __shared__ int sdeg[CHUNK];
        int j = blockIdx.x * CHUNK + t;
        int d = (j < N) ? degree[j] : -1;
        sdeg[t] = d;
        __syncthreads();
        if (j < N && d < DCAP && d >= 0) {
            int r = 0;
            for (int t2 = 0; t2 < t; ++t2) r += (sdeg[t2] == d);
            pos[j] = chunkBase[blockIdx.x * DCAP + d] + r;
        }
    } else {
        int d = DCAP + (blockIdx.x - numChunks) * CHUNK + t;
        if (d > E) return;
        if (hist[d] == 0) return;
        int base = 0;
        for (int d2 = 0; d2 < d; ++d2) base += hist[d2];
        int cnt = 0;
        for (int j = 0; j < N; ++j)
            if (degree[j] == d) pos[j] = base + cnt++;
    }
}
__global__ __launch_bounds__(256) void k_pack_ballot(const float* __restrict__ W,
                                                     uint32_t* __restrict__ Wbits,
                                                     long long G) {
    long long wv = ((long long)blockIdx.x * 256 + threadIdx.x) >> 6;
    long long nwv = ((long long)gridDim.x * 256) >> 6;
    int lane = threadIdx.x & 63;
    int k = lane >> 1, half = lane & 1;
    const uintv4* W4 = (const uintv4*)W;
    for (long long g = wv; g < G; g += nwv) {
        uintv4 u = W4[g * 64 + lane];
        unsigned long long m0 = __ballot((int)u.x < 0);
        unsigned long long m1 = __ballot((int)u.y < 0);
        unsigned long long m2 = __ballot((int)u.z < 0);
        unsigned long long m3 = __ballot((int)u.w < 0);
        if (lane < 8) {
            unsigned long long m = (k == 0) ? m0 : (k == 1) ? m1 : (k == 2) ? m2 : m3;
            Wbits[g * 8 + lane] = half ? (uint32_t)(m >> 32) : (uint32_t)m;
        }
    }
}
__global__ __launch_bounds__(256) void k_pack_linear(const float* __restrict__ W,
                                                     uint32_t* __restrict__ Wbits, long long NW) {
    long long widx = (long long)blockIdx.x * 256 + threadIdx.x;
    if (widx >= NW) return;
    const uintv4* src = (const uintv4*)(W + widx * 32);
    uint32_t word = 0;
    #pragma unroll
    for (int q = 0; q < 8; ++q) {
        uintv4 u = src[q];
        word |= (u.x >> 31) << (4 * q + 0);
        word |= (u.y >> 31) << (4 * q + 1);
        word |= (u.z >> 31) << (4 * q + 2);
        word |= (u.w >> 31) << (4 * q + 3);
    }
    Wbits[widx] = word;
}
__global__ void k_insert_nodes(const int* __restrict__ ei, unsigned int* __restrict__ tab,
                               int* __restrict__ uA, int* __restrict__ uB,
                               int* __restrict__ count, int E) {
    int e = blockIdx.x * blockDim.x + threadIdx.x;
    if (e >= E) return;
    int a = ei[e], b = ei[E + e];
    int r = min(a, b), c = max(a, b);
    unsigned int key = ((unsigned int)r << 16) | (unsigned int)c;
    unsigned int h = (key * 2654435761u) >> (32 - LOG_TAB);
    while (true) {
        unsigned int old = atomicCAS(&tab[h], KEMPTY, key);
        if (old == KEMPTY) { int idx = atomicAdd(count, 1); uA[idx] = r; uB[idx] = c; return; }
        if (old == key) return;
        h = (h + 1) & TAB_MASK;
    }
}

static inline size_t align256(size_t x) { return (x + 255) & ~(size_t)255; }

extern "C" void kernel_launch(void* const* d_in, const int* in_sizes, int n_in,
                              void* d_out, int out_size, void* d_ws, size_t ws_size,
                              hipStream_t stream) {
    const float* W  = (const float*)d_in[0];
    const int*   ei = (const int*)d_in[1];
    const int D = out_size;               // 1024
    const int N = in_sizes[0] / D;        // 50000
    const int E = in_sizes[1] / 2;        // 100000
    const int numChunks = (N + CHUNK - 1) / CHUNK;
    const int nLargeBlocks256 = (E + 1 - DCAP + 255) / 256;
    const long long ND = (long long)N * D;
    const long long NW = ND / 32;
    const long long G  = ND / 256;

    char* p = (char*)d_ws;
    int* bar          = (int*)p;          p += NSHARD * 32 * 4;   // 8 KB
    int* gen          = (int*)p;          p += NSHARD * 32 * 4;   // 8 KB
    char* zbase = p;                                               // fallback zero region
    int* degree       = (int*)p;          p += align256((size_t)N * 4);
    int* hist         = (int*)p;          p += align256((size_t)(E + 1) * 4);
    int* count        = (int*)p;          p += 256;
    int* neg          = (int*)p;          p += align256((size_t)D * 4);
    size_t zbytes = (size_t)(p - zbase);
    int* chunkHist    = (int*)p;          p += align256((size_t)numChunks * DCAP * 4);
    int* pos          = (int*)p;          p += align256((size_t)N * 4);
    unsigned int* tab = (unsigned int*)p; p += (size_t)TAB_SIZE * 4;
    int* uA           = (int*)p;          p += align256((size_t)E * 4);
    int* uB           = (int*)p;          p += align256((size_t)E * 4);
    uint32_t* Wbits   = (uint32_t*)p;     p += align256((size_t)NW * 4);

    int dev = 0;
    hipGetDevice(&dev);
    int cus = 0;
    hipDeviceGetAttribute(&cus, hipDeviceAttributeMultiprocessorCount, dev);
    int maxB = 0;
    hipOccupancyMaxActiveBlocksPerMultiprocessor(&maxB, k_mega, 256, 0);
    int NB = cus * maxB;
    if (NB > 2048) NB = 2048;

    bool useMega = (D % 256 == 0) && (D <= 1024) &&
                   (NB >= numChunks + nLargeBlocks256 + 64);

    if (useMega) {
        hipMemsetAsync(bar, 0, NSHARD * 32 * 4 * 2, stream);   // bar + gen
        const float* Wp = W; const int* eip = ei;
        int Np = N, Ep = E, Dp = D, nc = numChunks, nl = nLargeBlocks256, nb = NB;
        long long Gp = G;
        void* args[] = { (void*)&Wp, (void*)&eip, (void*)&degree, (void*)&hist,
                         (void*)&chunkHist, (void*)&pos, (void*)&tab, (void*)&uA,
                         (void*)&uB, (void*)&count, (void*)&neg, (void*)&Wbits,
                         (void*)&bar, (void*)&gen, (void*)&Np, (void*)&Ep,
                         (void*)&Dp, (void*)&nc, (void*)&nl, (void*)&Gp, (void*)&nb };
        hipError_t err = hipLaunchCooperativeKernel((void*)k_mega, dim3(NB), dim3(256),
                                                    args, 0, stream);
        if (err != hipSuccess) {
            (void)hipGetLastError();
            // occupancy-sized grid -> co-resident; plain launch as backup
            k_mega<<<NB, 256, 0, stream>>>(W, ei, degree, hist, chunkHist, pos, tab,
                                           uA, uB, count, neg, Wbits, bar, gen,
                                           N, E, D, numChunks, nLargeBlocks256, G, NB);
        }
        k_accum_bits<<<2048, 256, 0, stream>>>(Wbits, pos, uA, uB, count, neg, D);
        k_finalize<<<(D + 255) / 256, 256, 0, stream>>>(neg, count, (float*)d_out, D, 1);
    } else {
        hipMemsetAsync(zbase, 0, zbytes, stream);
        hipMemsetAsync(tab, 0xFF, (size_t)TAB_SIZE * 4, stream);
        k_degree<<<(E + 255) / 256, 256, 0, stream>>>(ei + E, degree, E);
        k_chunk_hist<<<numChunks, CHUNK, 0, stream>>>(degree, hist, chunkHist, N);
        k_chunk_prefix<<<1, DCAP, 0, stream>>>(hist, chunkHist, numChunks);
        int nLB = (E + 1 - DCAP + CHUNK - 1) / CHUNK;
        k_pos<<<numChunks + nLB, CHUNK, 0, stream>>>(degree, chunkHist, hist, pos,
                                                     N, E, numChunks);
        int permuted = (D % 256 == 0);
        if (permuted) k_pack_ballot<<<2048, 256, 0, stream>>>(W, Wbits, G);
        else          k_pack_linear<<<(int)((NW + 255) / 256), 256, 0, stream>>>(W, Wbits, NW);
        k_insert_nodes<<<(E + 255) / 256, 256, 0, stream>>>(ei, tab, uA, uB, count, E);
        k_accum_bits<<<2048, 256, 0, stream>>>(Wbits, pos, uA, uB, count, neg, D);
        k_finalize<<<(D + 255) / 256, 256, 0, stream>>>(neg, count, (float*)d_out, D, permuted);
    }
}

// Round 12
// 144.978 us; speedup vs baseline: 1.7857x; 1.7620x over previous
//
#include <hip/hip_runtime.h>
#include <stdint.h>

#define DCAP   128
#define CHUNK  1024
#define LOG_TAB 19
#define TAB_SIZE (1u << LOG_TAB)
#define TAB_MASK (TAB_SIZE - 1u)
#define KEMPTY 0xFFFFFFFFu

typedef unsigned int uintv4 __attribute__((ext_vector_type(4)));

// 1) FUSED: in-degree (col) + undirected-dedup hash insert (node ids).
//    One pass over ei; pos resolved later in accum.
__global__ void k_deg_ins(const int* __restrict__ ei, int* __restrict__ degree,
                          unsigned int* __restrict__ tab, int* __restrict__ uA,
                          int* __restrict__ uB, int* __restrict__ count, int E) {
    int e = blockIdx.x * blockDim.x + threadIdx.x;
    if (e >= E) return;
    int a = ei[e], b = ei[E + e];
    atomicAdd(&degree[b], 1);                      // bincount(edge_index[1])
    int r = min(a, b), c = max(a, b);
    unsigned int key = ((unsigned int)r << 16) | (unsigned int)c;  // N < 2^16
    unsigned int h = (key * 2654435761u) >> (32 - LOG_TAB);
    for (;;) {
        unsigned int old = atomicCAS(&tab[h], KEMPTY, key);
        if (old == KEMPTY) {                       // first occurrence
            int idx = atomicAdd(count, 1);
            uA[idx] = r; uB[idx] = c;
            return;
        }
        if (old == key) return;                    // duplicate
        h = (h + 1) & TAB_MASK;
    }
}

// 2a) per-chunk degree histogram in LDS (deg < DCAP); global hist atomics only
//     for the (never-occurring) deg >= DCAP tail.
__global__ __launch_bounds__(CHUNK) void k_chunk_hist(const int* __restrict__ degree,
                                                      int* __restrict__ hist,
                                                      int* __restrict__ chunkHist, int N) {
    __shared__ int sh[DCAP];
    int t = threadIdx.x;
    if (t < DCAP) sh[t] = 0;
    __syncthreads();
    int j = blockIdx.x * CHUNK + t;
    if (j < N) {
        int d = degree[j];
        if (d < DCAP) atomicAdd(&sh[d], 1);
        else          atomicAdd(&hist[d], 1);      // rare fallback path
    }
    __syncthreads();
    if (t < DCAP) chunkHist[blockIdx.x * DCAP + t] = sh[t];
}

// 2b) FUSED prefix+pos: each chunk-block recomputes its own per-degree base
//     from chunkHist (49x128 pipelined L2 reads), then stable intra-chunk rank.
//     Blocks >= numChunks: deg >= DCAP fallback via suffix sum of hist
//     (base(d) = N - sum_{d'>=d} hist[d']; never triggered for Poisson(2)).
__global__ __launch_bounds__(CHUNK) void k_pos(const int* __restrict__ degree,
                                               const int* __restrict__ chunkHist,
                                               const int* __restrict__ hist,
                                               int* __restrict__ pos,
                                               int N, int E, int numChunks) {
    int t = threadIdx.x;
    if ((int)blockIdx.x < numChunks) {
        __shared__ int sdeg[CHUNK];
        __shared__ int stot[DCAP];
        __shared__ int sbase[DCAP];
        int me = blockIdx.x;
        if (t < DCAP) {
            int tot = 0, pre = 0;
            for (int c = 0; c < numChunks; ++c) {
                int v = chunkHist[c * DCAP + t];
                pre += (c < me) ? v : 0;
                tot += v;
            }
            stot[t] = tot;
            sbase[t] = pre;
        }
        __syncthreads();
        if (t < DCAP) {
            int run = 0;
            for (int d2 = 0; d2 < t; ++d2) run += stot[d2];   // LDS scan, 128 steps
            sbase[t] += run;                                   // global base for my chunk
        }
        int j = me * CHUNK + t;
        int d = (j < N) ? degree[j] : -1;
        sdeg[t] = d;
        __syncthreads();
        if (j < N && d >= 0 && d < DCAP) {
            int r = 0;
            for (int t2 = 0; t2 < t; ++t2) r += (sdeg[t2] == d);
            pos[j] = sbase[d] + r;
        }
    } else {
        int d = DCAP + ((int)blockIdx.x - numChunks) * CHUNK + t;
        if (d > E) return;
        if (hist[d] == 0) return;
        long long suf = 0;
        for (int d2 = d; d2 <= E; ++d2) suf += hist[d2];
        int base = N - (int)suf;
        int cnt = 0;
        for (int j = 0; j < N; ++j)
            if (degree[j] == d) pos[j] = base + cnt++;
    }
}

// 3) persistent-wave ballot-pack, permuted bit layout (verified R5..R9):
//    word g*8 + 2k+half, bit b  <->  float g*256 + 128*half + 4b + k.
//    Two-phase body: PACK_DEPTH unconditional clamp-addressed dwordx4 loads
//    in flight, then ballots; only the store is predicated.
#define PACK_DEPTH 8
__global__ __launch_bounds__(256) void k_pack_ballot(const float* __restrict__ W,
                                                     uint32_t* __restrict__ Wbits,
                                                     long long G) {
    long long wv0 = ((long long)blockIdx.x * 256 + threadIdx.x) >> 6;
    long long nwv = ((long long)gridDim.x * 256) >> 6;
    int lane = threadIdx.x & 63;
    int k = lane >> 1, half = lane & 1;          // meaningful when lane < 8
    const uintv4* W4 = (const uintv4*)W;
    for (long long gb = wv0 * PACK_DEPTH; gb < G; gb += nwv * PACK_DEPTH) {
        uintv4 u[PACK_DEPTH];
        #pragma unroll
        for (int s = 0; s < PACK_DEPTH; ++s) {
            long long g = gb + s;
            if (g >= G) g = G - 1;               // clamp: load stays in-bounds
            u[s] = W4[g * 64 + lane];
        }
        #pragma unroll
        for (int s = 0; s < PACK_DEPTH; ++s) {
            long long g = gb + s;
            unsigned long long m0 = __ballot((int)u[s].x < 0);
            unsigned long long m1 = __ballot((int)u[s].y < 0);
            unsigned long long m2 = __ballot((int)u[s].z < 0);
            unsigned long long m3 = __ballot((int)u[s].w < 0);
            if (g < G && lane < 8) {
                unsigned long long m = (k == 0) ? m0 : (k == 1) ? m1
                                     : (k == 2) ? m2 : m3;
                Wbits[g * 8 + lane] = half ? (uint32_t)(m >> 32) : (uint32_t)m;
            }
        }
    }
}

// 3-alt) linear-layout pack fallback (only if D % 256 != 0)
__global__ __launch_bounds__(256) void k_pack_linear(const float* __restrict__ W,
                                                     uint32_t* __restrict__ Wbits, long long NW) {
    long long widx = (long long)blockIdx.x * 256 + threadIdx.x;
    if (widx >= NW) return;
    const uintv4* src = (const uintv4*)(W + widx * 32);
    uint32_t word = 0;
    #pragma unroll
    for (int q = 0; q < 8; ++q) {
        uintv4 u = src[q];
        word |= (u.x >> 31) << (4 * q + 0);
        word |= (u.y >> 31) << (4 * q + 1);
        word |= (u.z >> 31) << (4 * q + 2);
        word |= (u.w >> 31) << (4 * q + 3);
    }
    Wbits[widx] = word;
}

// 4) accum: neg[w*32+d] += xor-popcount over unique edges; pos resolved here
//    (broadcast L2 loads). NO fences — kernel boundary provides coherence.
__global__ __launch_bounds__(256) void k_accum_bits(const uint32_t* __restrict__ Wbits,
                                                    const int* __restrict__ pos,
                                                    const int* __restrict__ uA,
                                                    const int* __restrict__ uB,
                                                    const int* __restrict__ count,
                                                    int* __restrict__ neg, int D) {
    __shared__ int sneg[1024];
    int t = threadIdx.x, w = t & 31, slot = t >> 5;
    int wpr = D / 32;                       // requires D <= 1024
    for (int i = t; i < D; i += 256) sneg[i] = 0;
    __syncthreads();
    int cnt = *count;
    int cnts[32];
    #pragma unroll
    for (int d = 0; d < 32; ++d) cnts[d] = 0;
    if (w < wpr) {
        for (int base = blockIdx.x * 8; base < cnt; base += gridDim.x * 8) {
            int e = base + slot;
            if (e < cnt) {
                size_t ra = (size_t)pos[uA[e]] * wpr;
                size_t rb = (size_t)pos[uB[e]] * wpr;
                uint32_t x = Wbits[ra + w] ^ Wbits[rb + w];
                #pragma unroll
                for (int d = 0; d < 32; ++d) cnts[d] += (x >> d) & 1u;
            }
        }
        #pragma unroll
        for (int d = 0; d < 32; ++d) atomicAdd(&sneg[w * 32 + d], cnts[d]);
    }
    __syncthreads();
    for (int i = t; i < D; i += 256)
        if (sneg[i]) atomicAdd(&neg[i], sneg[i]);
}

// 5) out[d] = cnt - 2*neg[map(d)]  (exact integer, fits float32)
__global__ void k_finalize(const int* __restrict__ neg, const int* __restrict__ count,
                           float* __restrict__ out, int D, int permuted) {
    int d = blockIdx.x * blockDim.x + threadIdx.x;
    if (d >= D) return;
    int ni;
    if (permuted) {
        int off = d & 255, q = d >> 8;
        int k = off & 3, l = off >> 2, half = l >> 5, b = l & 31;
        ni = (q * 8 + 2 * k + half) * 32 + b;
    } else {
        ni = d;
    }
    out[d] = (float)(*count - 2 * neg[ni]);
}

static inline size_t align256(size_t x) { return (x + 255) & ~(size_t)255; }

extern "C" void kernel_launch(void* const* d_in, const int* in_sizes, int n_in,
                              void* d_out, int out_size, void* d_ws, size_t ws_size,
                              hipStream_t stream) {
    const float* W  = (const float*)d_in[0];
    const int*   ei = (const int*)d_in[1];
    const int D = out_size;               // 1024
    const int N = in_sizes[0] / D;        // 50000 (== num_nodes)
    const int E = in_sizes[1] / 2;        // 100000
    const int numChunks = (N + CHUNK - 1) / CHUNK;
    const long long ND = (long long)N * D;
    const long long NW = ND / 32;
    const long long G  = ND / 256;

    // zero-region: [degree | hist | count | neg] -> ONE memset
    char* p = (char*)d_ws;
    char* zbase = p;
    int* degree       = (int*)p;          p += align256((size_t)N * 4);
    int* hist         = (int*)p;          p += align256((size_t)(E + 1) * 4);
    int* count        = (int*)p;          p += 256;
    int* neg          = (int*)p;          p += align256((size_t)D * 4);
    size_t zbytes = (size_t)(p - zbase);
    int* chunkHist    = (int*)p;          p += align256((size_t)numChunks * DCAP * 4);
    int* pos          = (int*)p;          p += align256((size_t)N * 4);
    unsigned int* tab = (unsigned int*)p; p += (size_t)TAB_SIZE * 4;
    int* uA           = (int*)p;          p += align256((size_t)E * 4);
    int* uB           = (int*)p;          p += align256((size_t)E * 4);
    uint32_t* Wbits   = (uint32_t*)p;     p += align256((size_t)NW * 4);

    hipMemsetAsync(zbase, 0, zbytes, stream);
    hipMemsetAsync(tab, 0xFF, (size_t)TAB_SIZE * 4, stream);

    k_deg_ins<<<(E + 255) / 256, 256, 0, stream>>>(ei, degree, tab, uA, uB, count, E);
    k_chunk_hist<<<numChunks, CHUNK, 0, stream>>>(degree, hist, chunkHist, N);
    int nLargeBlocks = (E + 1 - DCAP + CHUNK - 1) / CHUNK;
    k_pos<<<numChunks + nLargeBlocks, CHUNK, 0, stream>>>(degree, chunkHist, hist,
                                                          pos, N, E, numChunks);

    int permuted = (D % 256 == 0);
    if (permuted) {
        k_pack_ballot<<<2048, 256, 0, stream>>>(W, Wbits, G);
    } else {
        k_pack_linear<<<(int)((NW + 255) / 256), 256, 0, stream>>>(W, Wbits, NW);
    }

    k_accum_bits<<<2048, 256, 0, stream>>>(Wbits, pos, uA, uB, count, neg, D);
    k_finalize<<<(D + 255) / 256, 256, 0, stream>>>(neg, count, (float*)d_out, D, permuted);
}